// Round 1
// baseline (2454.725 us; speedup 1.0000x reference)
//
#include <hip/hip_runtime.h>
#include <cstdint>

// Problem constants
#define TOKENS   8192
#define NEXP     64
#define TOPK     8
#define HID      2048
#define INTER    768
#define CAP      2048          // per-expert row capacity (mean count = 1024)
#define TKROWS   (TOKENS*TOPK) // 65536

typedef unsigned short u16;
typedef __attribute__((ext_vector_type(8))) short bf16x8;
typedef __attribute__((ext_vector_type(4))) float f32x4;

__device__ __forceinline__ u16 bf16_rte(float f) {
    unsigned u = __builtin_bit_cast(unsigned, f);
    u += 0x7fffu + ((u >> 16) & 1u);
    return (u16)(u >> 16);
}

// ---------------------------------------------------------------- routing ---
__global__ void route_kernel(const float* __restrict__ logits,
                             int* __restrict__ counts,
                             int* __restrict__ pair_token,
                             float* __restrict__ pair_w) {
    int t = blockIdx.x;
    int lane = threadIdx.x; // 64 threads = 1 wave
    float cur = logits[t * NEXP + lane];

    float vals[TOPK];
    int ids[TOPK];
    #pragma unroll
    for (int s = 0; s < TOPK; s++) {
        float m = cur; int mi = lane;
        #pragma unroll
        for (int off = 32; off > 0; off >>= 1) {
            float ov = __shfl_xor(m, off);
            int   oi = __shfl_xor(mi, off);
            if (ov > m || (ov == m && oi < mi)) { m = ov; mi = oi; }
        }
        vals[s] = m; ids[s] = mi;
        if (lane == mi) cur = -3.4e38f;
    }
    // softmax over the 8 (vals[0] is the max)
    float ex[TOPK]; float sum = 0.f;
    #pragma unroll
    for (int s = 0; s < TOPK; s++) { ex[s] = __expf(vals[s] - vals[0]); sum += ex[s]; }
    if (lane < TOPK) {
        float w = ex[lane] / sum;
        int e = ids[lane];
        int slot = atomicAdd(&counts[e], 1);
        pair_token[e * CAP + slot] = t;
        pair_w[e * CAP + slot] = w;
    }
}

__global__ void scan_kernel(const int* __restrict__ counts, int* __restrict__ offs) {
    if (threadIdx.x == 0) {
        int s = 0;
        for (int e = 0; e < NEXP; e++) { offs[e] = s; s += counts[e]; }
    }
}

// ------------------------------------------------------------ conversions ---
__global__ void cvt_x_kernel(const float* __restrict__ x, u16* __restrict__ xb) {
    int i = blockIdx.x * blockDim.x + threadIdx.x; // handles 8 floats
    const float4* src = (const float4*)x;
    float4 a = src[i * 2 + 0];
    float4 b = src[i * 2 + 1];
    ushort4 o0, o1;
    o0.x = bf16_rte(a.x); o0.y = bf16_rte(a.y); o0.z = bf16_rte(a.z); o0.w = bf16_rte(a.w);
    o1.x = bf16_rte(b.x); o1.y = bf16_rte(b.y); o1.z = bf16_rte(b.z); o1.w = bf16_rte(b.w);
    ((ushort4*)xb)[i * 2 + 0] = o0;
    ((ushort4*)xb)[i * 2 + 1] = o1;
}

// transpose+convert: in [E][R][C] fp32 -> out [E][C][R] bf16
__global__ void transpose_cvt_kernel(const float* __restrict__ in, u16* __restrict__ out,
                                     int R, int C) {
    __shared__ float tile[64][65];
    int e = blockIdx.z;
    size_t ebase = (size_t)e * R * C;
    int c0t = blockIdx.x * 64, r0t = blockIdx.y * 64;
    int lc = threadIdx.x & 63, lr4 = threadIdx.x >> 6;
    #pragma unroll
    for (int rr = 0; rr < 64; rr += 4)
        tile[lr4 + rr][lc] = in[ebase + (size_t)(r0t + lr4 + rr) * C + c0t + lc];
    __syncthreads();
    int lrr = threadIdx.x & 63, lc4 = threadIdx.x >> 6;
    #pragma unroll
    for (int cc = 0; cc < 64; cc += 4)
        out[ebase + (size_t)(c0t + lc4 + cc) * R + r0t + lrr] = bf16_rte(tile[lrr][lc4 + cc]);
}

// ------------------------------------------------------------------ GEMM1 ---
// h[base+row][n] = silu(x@gateT) * (x@upT), per expert. Tiles 128x128x64.
__global__ __launch_bounds__(256, 2)
void gemm1_kernel(const u16* __restrict__ xb,   // [TOKENS][HID] bf16
                  const u16* __restrict__ gT,   // [E][INTER][HID] bf16
                  const u16* __restrict__ uT,   // [E][INTER][HID] bf16
                  const int* __restrict__ counts,
                  const int* __restrict__ offs,
                  const int* __restrict__ pair_token,
                  u16* __restrict__ hbuf) {     // [TKROWS][INTER] bf16
    const int NT = INTER / 128; // 6
    const int MT = CAP / 128;   // 16
    int bid = blockIdx.x;
    int e  = bid / (MT * NT);
    int r2 = bid % (MT * NT);
    int mt = r2 / NT, nt = r2 % NT;
    int count = counts[e];
    if (mt * 128 >= count) return;

    __shared__ u16 As[128 * 64];
    __shared__ u16 Bg[128 * 64];
    __shared__ u16 Bu[128 * 64];
    __shared__ int toks[128];

    int tid = threadIdx.x;
    if (tid < 128) {
        int row = mt * 128 + tid;
        int cr = row < count ? row : count - 1;
        toks[tid] = pair_token[e * CAP + cr];
    }
    int base = offs[e];

    int wave = tid >> 6, lane = tid & 63;
    int m_off = (wave & 1) * 64, n_off = (wave >> 1) * 64;
    int lrow = lane & 15, quad = lane >> 4;

    f32x4 accg[4][4];
    f32x4 accu[4][4];
    #pragma unroll
    for (int i = 0; i < 4; i++)
        #pragma unroll
        for (int j = 0; j < 4; j++) {
            accg[i][j] = (f32x4){0.f, 0.f, 0.f, 0.f};
            accu[i][j] = (f32x4){0.f, 0.f, 0.f, 0.f};
        }

    const u16* gbase = gT + (size_t)e * INTER * HID + (size_t)(nt * 128) * HID;
    const u16* ubase = uT + (size_t)e * INTER * HID + (size_t)(nt * 128) * HID;

    for (int k0 = 0; k0 < HID; k0 += 64) {
        __syncthreads();
        #pragma unroll
        for (int p = 0; p < 4; p++) {
            int c = tid + 256 * p;
            int r = c >> 3, ko = (c & 7) * 8;
            uint4 av = *(const uint4*)(xb + (size_t)toks[r] * HID + k0 + ko);
            uint4 gv = *(const uint4*)(gbase + (size_t)r * HID + k0 + ko);
            uint4 uv = *(const uint4*)(ubase + (size_t)r * HID + k0 + ko);
            *(uint4*)(&As[r * 64 + ko]) = av;
            *(uint4*)(&Bg[r * 64 + ko]) = gv;
            *(uint4*)(&Bu[r * 64 + ko]) = uv;
        }
        __syncthreads();
        #pragma unroll
        for (int kh = 0; kh < 2; kh++) {
            bf16x8 af[4], bg[4], bu[4];
            #pragma unroll
            for (int i = 0; i < 4; i++)
                af[i] = *(const bf16x8*)(&As[(m_off + i * 16 + lrow) * 64 + kh * 32 + quad * 8]);
            #pragma unroll
            for (int j = 0; j < 4; j++) {
                bg[j] = *(const bf16x8*)(&Bg[(n_off + j * 16 + lrow) * 64 + kh * 32 + quad * 8]);
                bu[j] = *(const bf16x8*)(&Bu[(n_off + j * 16 + lrow) * 64 + kh * 32 + quad * 8]);
            }
            #pragma unroll
            for (int i = 0; i < 4; i++)
                #pragma unroll
                for (int j = 0; j < 4; j++) {
                    accg[i][j] = __builtin_amdgcn_mfma_f32_16x16x32_bf16(af[i], bg[j], accg[i][j], 0, 0, 0);
                    accu[i][j] = __builtin_amdgcn_mfma_f32_16x16x32_bf16(af[i], bu[j], accu[i][j], 0, 0, 0);
                }
        }
    }

    // epilogue: silu(g)*u -> bf16 h
    #pragma unroll
    for (int i = 0; i < 4; i++)
        #pragma unroll
        for (int j = 0; j < 4; j++)
            #pragma unroll
            for (int v = 0; v < 4; v++) {
                int row = m_off + i * 16 + quad * 4 + v;
                int col = n_off + j * 16 + lrow;
                int grow = mt * 128 + row;
                if (grow < count) {
                    float g = accg[i][j][v], u = accu[i][j][v];
                    float hval = g / (1.f + __expf(-g)) * u;
                    hbuf[(size_t)(base + grow) * INTER + nt * 128 + col] = bf16_rte(hval);
                }
            }
}

// ------------------------------------------------------------------ GEMM2 ---
__global__ __launch_bounds__(256, 2)
void gemm2_kernel(const u16* __restrict__ hbuf, // [TKROWS][INTER] bf16
                  const u16* __restrict__ dT,   // [E][HID][INTER] bf16
                  const int* __restrict__ counts,
                  const int* __restrict__ offs,
                  const int* __restrict__ pair_token,
                  const float* __restrict__ pair_w,
                  float* __restrict__ out) {    // [TOKENS][HID] fp32 (atomic)
    const int NT = HID / 128;  // 16
    const int MT = CAP / 128;  // 16
    int bid = blockIdx.x;
    int e  = bid / (MT * NT);
    int r2 = bid % (MT * NT);
    int mt = r2 / NT, nt = r2 % NT;
    int count = counts[e];
    if (mt * 128 >= count) return;

    __shared__ u16 As[128 * 64];
    __shared__ u16 Bs[128 * 64];
    __shared__ int toks[128];
    __shared__ float wrow[128];

    int tid = threadIdx.x;
    if (tid < 128) {
        int row = mt * 128 + tid;
        int cr = row < count ? row : count - 1;
        toks[tid] = pair_token[e * CAP + cr];
        wrow[tid] = pair_w[e * CAP + cr];
    }
    int base = offs[e];

    int wave = tid >> 6, lane = tid & 63;
    int m_off = (wave & 1) * 64, n_off = (wave >> 1) * 64;
    int lrow = lane & 15, quad = lane >> 4;

    f32x4 acc[4][4];
    #pragma unroll
    for (int i = 0; i < 4; i++)
        #pragma unroll
        for (int j = 0; j < 4; j++) acc[i][j] = (f32x4){0.f, 0.f, 0.f, 0.f};

    const u16* bbase = dT + (size_t)e * HID * INTER + (size_t)(nt * 128) * INTER;

    for (int k0 = 0; k0 < INTER; k0 += 64) {
        __syncthreads();
        #pragma unroll
        for (int p = 0; p < 4; p++) {
            int c = tid + 256 * p;
            int r = c >> 3, ko = (c & 7) * 8;
            int grow = mt * 128 + r;
            int cr = grow < count ? grow : count - 1;
            uint4 av = *(const uint4*)(hbuf + (size_t)(base + cr) * INTER + k0 + ko);
            uint4 bv = *(const uint4*)(bbase + (size_t)r * INTER + k0 + ko);
            *(uint4*)(&As[r * 64 + ko]) = av;
            *(uint4*)(&Bs[r * 64 + ko]) = bv;
        }
        __syncthreads();
        #pragma unroll
        for (int kh = 0; kh < 2; kh++) {
            bf16x8 af[4], bf[4];
            #pragma unroll
            for (int i = 0; i < 4; i++)
                af[i] = *(const bf16x8*)(&As[(m_off + i * 16 + lrow) * 64 + kh * 32 + quad * 8]);
            #pragma unroll
            for (int j = 0; j < 4; j++)
                bf[j] = *(const bf16x8*)(&Bs[(n_off + j * 16 + lrow) * 64 + kh * 32 + quad * 8]);
            #pragma unroll
            for (int i = 0; i < 4; i++)
                #pragma unroll
                for (int j = 0; j < 4; j++)
                    acc[i][j] = __builtin_amdgcn_mfma_f32_16x16x32_bf16(af[i], bf[j], acc[i][j], 0, 0, 0);
        }
    }

    #pragma unroll
    for (int i = 0; i < 4; i++)
        #pragma unroll
        for (int j = 0; j < 4; j++)
            #pragma unroll
            for (int v = 0; v < 4; v++) {
                int row = m_off + i * 16 + quad * 4 + v;
                int col = n_off + j * 16 + lrow;
                int grow = mt * 128 + row;
                if (grow < count) {
                    float val = acc[i][j][v] * wrow[row];
                    atomicAdd(out + (size_t)toks[row] * HID + nt * 128 + col, val);
                }
            }
}

// ------------------------------------------------------------------ launch ---
extern "C" void kernel_launch(void* const* d_in, const int* in_sizes, int n_in,
                              void* d_out, int out_size, void* d_ws, size_t ws_size,
                              hipStream_t stream) {
    const float* x      = (const float*)d_in[0];
    const float* logits = (const float*)d_in[1];
    const float* gate   = (const float*)d_in[2];
    const float* up     = (const float*)d_in[3];
    const float* down   = (const float*)d_in[4];
    float* out = (float*)d_out;
    char* ws = (char*)d_ws;

    // ws layout (bytes)
    constexpr size_t OFF_WGT = 0;                       // gate^T bf16 (later down^T), 201326592
    constexpr size_t OFF_WUT = 201326592;               // up^T bf16, 201326592
    constexpr size_t OFF_XB  = 402653184;               // x bf16, 33554432
    constexpr size_t OFF_HB  = 436207616;               // h bf16, 100663296
    constexpr size_t OFF_CNT = 536870912;               // counts (256B)
    constexpr size_t OFF_OFS = OFF_CNT + 256;           // offsets (256B)
    constexpr size_t OFF_PT  = OFF_CNT + 512;           // pair_token (524288B)
    constexpr size_t OFF_PW  = OFF_PT + 524288;         // pair_w (524288B)
    constexpr size_t WS_NEED = OFF_PW + 524288;
    if (ws_size < WS_NEED) return; // leaves out poisoned -> loud failure

    u16*   wgT    = (u16*)(ws + OFF_WGT);
    u16*   wuT    = (u16*)(ws + OFF_WUT);
    u16*   xb     = (u16*)(ws + OFF_XB);
    u16*   hb     = (u16*)(ws + OFF_HB);
    int*   counts = (int*)(ws + OFF_CNT);
    int*   offs   = (int*)(ws + OFF_OFS);
    int*   ptok   = (int*)(ws + OFF_PT);
    float* pw     = (float*)(ws + OFF_PW);

    hipMemsetAsync(counts, 0, 256, stream);
    hipMemsetAsync(out, 0, (size_t)out_size * 4, stream);

    route_kernel<<<TOKENS, 64, 0, stream>>>(logits, counts, ptok, pw);
    scan_kernel<<<1, 64, 0, stream>>>(counts, offs);
    cvt_x_kernel<<<(TOKENS * HID / 8) / 256, 256, 0, stream>>>(x, xb);
    transpose_cvt_kernel<<<dim3(INTER / 64, HID / 64, NEXP), 256, 0, stream>>>(gate, wgT, HID, INTER);
    transpose_cvt_kernel<<<dim3(INTER / 64, HID / 64, NEXP), 256, 0, stream>>>(up, wuT, HID, INTER);
    gemm1_kernel<<<NEXP * (CAP / 128) * (INTER / 128), 256, 0, stream>>>(xb, wgT, wuT, counts, offs, ptok, hb);
    // reuse gate^T region for down^T (stream-ordered after gemm1)
    transpose_cvt_kernel<<<dim3(HID / 64, INTER / 64, NEXP), 256, 0, stream>>>(down, wgT, INTER, HID);
    gemm2_kernel<<<NEXP * (CAP / 128) * (HID / 128), 256, 0, stream>>>(hb, wgT, counts, offs, ptok, pw, out);
}